// Round 1
// baseline (356.846 us; speedup 1.0000x reference)
//
#include <hip/hip_runtime.h>

#define N_NODES 100000
#define NF      128
#define NE      600000
#define NG      1000
#define EPSF    1e-5f

#define SROWS   64           // rows per block in stats pass
#define SCHUNK  1024         // elements per scan block
#define SCAN_NB ((N_NODES + SCHUNK - 1) / SCHUNK)   // 98

// ---------------- degree count ----------------
__global__ void k_deg(const int* __restrict__ dst, int* __restrict__ deg) {
    int e = blockIdx.x * 256 + threadIdx.x;
    if (e < NE) atomicAdd(&deg[dst[e]], 1);
}

// ---------------- streaming stats: batch sums + per-graph run-flush ----------------
__global__ __launch_bounds__(64) void k_stats(
    const float* __restrict__ x, const int* __restrict__ gid,
    float* __restrict__ bsum, float* __restrict__ bsq,
    float* __restrict__ gsum, float* __restrict__ gsq, int* __restrict__ cnt)
{
    const int lane = threadIdx.x;        // 0..63
    const int f = lane * 2;
    int r0 = blockIdx.x * SROWS;
    int r1 = r0 + SROWS; if (r1 > N_NODES) r1 = N_NODES;

    float bsx = 0.f, bsy = 0.f, bqx = 0.f, bqy = 0.f;
    float gsx = 0.f, gsy = 0.f, gqx = 0.f, gqy = 0.f;
    int cur = gid[r0];
    int runStart = r0;

    for (int r = r0; r < r1; ++r) {
        int g = gid[r];                  // uniform across the wave
        if (g != cur) {
            atomicAdd(&gsum[cur * NF + f],     gsx);
            atomicAdd(&gsum[cur * NF + f + 1], gsy);
            atomicAdd(&gsq [cur * NF + f],     gqx);
            atomicAdd(&gsq [cur * NF + f + 1], gqy);
            if (lane == 0) atomicAdd(&cnt[cur], r - runStart);
            gsx = gsy = gqx = gqy = 0.f;
            cur = g; runStart = r;
        }
        const float2 v = *reinterpret_cast<const float2*>(x + (size_t)r * NF + f);
        bsx += v.x; bsy += v.y; bqx += v.x * v.x; bqy += v.y * v.y;
        gsx += v.x; gsy += v.y; gqx += v.x * v.x; gqy += v.y * v.y;
    }
    atomicAdd(&gsum[cur * NF + f],     gsx);
    atomicAdd(&gsum[cur * NF + f + 1], gsy);
    atomicAdd(&gsq [cur * NF + f],     gqx);
    atomicAdd(&gsq [cur * NF + f + 1], gqy);
    if (lane == 0) atomicAdd(&cnt[cur], r1 - runStart);

    atomicAdd(&bsum[f],     bsx);
    atomicAdd(&bsum[f + 1], bsy);
    atomicAdd(&bsq [f],     bqx);
    atomicAdd(&bsq [f + 1], bqy);
}

// ---------------- 3-kernel exclusive scan of deg -> off ----------------
__global__ void k_scan1(const int* __restrict__ deg, int* __restrict__ bsums) {
    __shared__ int sdata[256];
    int b = blockIdx.x, t = threadIdx.x;
    int base = b * SCHUNK;
    int s = 0;
#pragma unroll
    for (int k = 0; k < 4; ++k) {
        int i = base + t * 4 + k;
        if (i < N_NODES) s += deg[i];
    }
    sdata[t] = s; __syncthreads();
    for (int st = 128; st > 0; st >>= 1) {
        if (t < st) sdata[t] += sdata[t + st];
        __syncthreads();
    }
    if (t == 0) bsums[b] = sdata[0];
}

__global__ void k_scan2(int* __restrict__ bsums) {
    if (threadIdx.x == 0 && blockIdx.x == 0) {
        int acc = 0;
        for (int i = 0; i < SCAN_NB; ++i) { int v = bsums[i]; bsums[i] = acc; acc += v; }
    }
}

__global__ void k_scan3(const int* __restrict__ deg, const int* __restrict__ bsums,
                        int* __restrict__ off) {
    __shared__ int sdata[256];
    int b = blockIdx.x, t = threadIdx.x;
    int base = b * SCHUNK;
    int loc[4]; int s = 0;
#pragma unroll
    for (int k = 0; k < 4; ++k) {
        int i = base + t * 4 + k;
        loc[k] = (i < N_NODES) ? deg[i] : 0;
        s += loc[k];
    }
    sdata[t] = s; __syncthreads();
    for (int st = 1; st < 256; st <<= 1) {
        int v = (t >= st) ? sdata[t - st] : 0;
        __syncthreads();
        sdata[t] += v;
        __syncthreads();
    }
    int run = bsums[b] + (sdata[t] - s);   // exclusive prefix for this thread's 4 elems
#pragma unroll
    for (int k = 0; k < 4; ++k) {
        int i = base + t * 4 + k;
        if (i < N_NODES) { off[i] = run; run += loc[k]; }
    }
    if (b == 0 && t == 0) off[N_NODES] = NE;
}

// ---------------- CSR fill ----------------
__global__ void k_fill(const int* __restrict__ src, const int* __restrict__ dst,
                       const int* __restrict__ off, int* __restrict__ cursor,
                       int* __restrict__ nbr) {
    int e = blockIdx.x * 256 + threadIdx.x;
    if (e < NE) {
        int d = dst[e];
        int p = atomicAdd(&cursor[d], 1);
        nbr[off[d] + p] = src[e];
    }
}

// ---------------- fused final: all four norms + lambda softmax + affine ----------------
__global__ __launch_bounds__(256) void k_final(
    const float* __restrict__ x, const float* __restrict__ gamma, const float* __restrict__ beta,
    const float* __restrict__ lb, const float* __restrict__ lg,
    const float* __restrict__ la, const float* __restrict__ ln,
    const int* __restrict__ gid,
    const float* __restrict__ bsum, const float* __restrict__ bsq,
    const float* __restrict__ gsum, const float* __restrict__ gsq,
    const int* __restrict__ cnt, const int* __restrict__ off,
    const int* __restrict__ nbr, float* __restrict__ out)
{
    const int wave = threadIdx.x >> 6;
    const int lane = threadIdx.x & 63;
    const int i = blockIdx.x * 4 + wave;
    if (i >= N_NODES) return;
    const int f = lane * 2;

    const float2 xi = *reinterpret_cast<const float2*>(x + (size_t)i * NF + f);

    // ---- batch norm (var NOT clamped, matching reference) ----
    const float invN = 1.0f / (float)N_NODES;
    float mbx = bsum[f] * invN,     mby = bsum[f + 1] * invN;
    float vbx = bsq[f] * invN - mbx * mbx;
    float vby = bsq[f + 1] * invN - mby * mby;
    float xbx = (xi.x - mbx) * rsqrtf(vbx + EPSF);
    float xby = (xi.y - mby) * rsqrtf(vby + EPSF);

    // ---- graph norm ----
    const int g = gid[i];
    float c = (float)cnt[g]; if (c < 1.f) c = 1.f;
    float rc = 1.0f / c;
    float mgx = gsum[g * NF + f] * rc,     mgy = gsum[g * NF + f + 1] * rc;
    float vgx = gsq[g * NF + f] * rc - mgx * mgx;     if (vgx < 0.f) vgx = 0.f;
    float vgy = gsq[g * NF + f + 1] * rc - mgy * mgy; if (vgy < 0.f) vgy = 0.f;
    float xgx = (xi.x - mgx) * rsqrtf(vgx + EPSF);
    float xgy = (xi.y - mgy) * rsqrtf(vgy + EPSF);

    // ---- node norm (layernorm across F within the wave) ----
    float s = xi.x + xi.y;
#pragma unroll
    for (int d = 1; d < 64; d <<= 1) s += __shfl_xor(s, d, 64);
    const float mn = s * (1.0f / NF);
    float dxx = xi.x - mn, dyy = xi.y - mn;
    float q = dxx * dxx + dyy * dyy;
#pragma unroll
    for (int d = 1; d < 64; d <<= 1) q += __shfl_xor(q, d, 64);
    const float rvn = rsqrtf(q * (1.0f / NF) + EPSF);
    float xnx = dxx * rvn, xny = dyy * rvn;

    // ---- adjacency norm: gather in-neighbor rows via CSR ----
    int e0 = off[i], e1 = off[i + 1];
    float asx = 0.f, asy = 0.f, aqx = 0.f, aqy = 0.f;
    for (int e = e0; e < e1; ++e) {
        int j = nbr[e];
        const float2 v = *reinterpret_cast<const float2*>(x + (size_t)j * NF + f);
        asx += v.x; asy += v.y; aqx += v.x * v.x; aqy += v.y * v.y;
    }
    float dgc = (float)(e1 - e0); if (dgc < 1.f) dgc = 1.f;
    float rdg = 1.0f / dgc;
    float max_ = asx * rdg, may_ = asy * rdg;
    float vax = aqx * rdg - max_ * max_; if (vax < 0.f) vax = 0.f;
    float vay = aqy * rdg - may_ * may_; if (vay < 0.f) vay = 0.f;
    float xax = (xi.x - max_) * rsqrtf(vax + EPSF);
    float xay = (xi.y - may_) * rsqrtf(vay + EPSF);

    // ---- lambda softmax per feature + affine ----
    float outx, outy;
    {
        float l0 = lb[f], l1 = lg[f], l2 = la[f], l3 = ln[f];
        float m = fmaxf(fmaxf(l0, l1), fmaxf(l2, l3));
        float w0 = __expf(l0 - m), w1 = __expf(l1 - m), w2 = __expf(l2 - m), w3 = __expf(l3 - m);
        float rs = 1.0f / (w0 + w1 + w2 + w3);
        outx = gamma[f] * ((w0 * xbx + w1 * xgx + w2 * xax + w3 * xnx) * rs) + beta[f];
    }
    {
        int f1 = f + 1;
        float l0 = lb[f1], l1 = lg[f1], l2 = la[f1], l3 = ln[f1];
        float m = fmaxf(fmaxf(l0, l1), fmaxf(l2, l3));
        float w0 = __expf(l0 - m), w1 = __expf(l1 - m), w2 = __expf(l2 - m), w3 = __expf(l3 - m);
        float rs = 1.0f / (w0 + w1 + w2 + w3);
        outy = gamma[f1] * ((w0 * xby + w1 * xgy + w2 * xay + w3 * xny) * rs) + beta[f1];
    }
    *reinterpret_cast<float2*>(out + (size_t)i * NF + f) = make_float2(outx, outy);
}

extern "C" void kernel_launch(void* const* d_in, const int* in_sizes, int n_in,
                              void* d_out, int out_size, void* d_ws, size_t ws_size,
                              hipStream_t stream) {
    const float* x     = (const float*)d_in[0];
    const float* gamma = (const float*)d_in[1];
    const float* beta  = (const float*)d_in[2];
    const float* lb    = (const float*)d_in[3];
    const float* lg    = (const float*)d_in[4];
    const float* la    = (const float*)d_in[5];
    const float* ln    = (const float*)d_in[6];
    const int*   gid   = (const int*)d_in[7];
    const int*   esrc  = (const int*)d_in[8];
    const int*   edst  = (const int*)d_in[9];
    float*       out   = (float*)d_out;

    // ---- workspace layout (4B units) ----
    float* ws    = (float*)d_ws;
    float* bsum  = ws;                        // NF
    float* bsq   = bsum + NF;                 // NF
    float* gsum  = bsq + NF;                  // NG*NF
    float* gsq   = gsum + (size_t)NG * NF;    // NG*NF
    int*   cnt   = (int*)(gsq + (size_t)NG * NF); // NG
    int*   deg   = cnt + NG;                  // N
    int*   cursor= deg + N_NODES;             // N
    // zeroed region ends here
    int*   off   = cursor + N_NODES;          // N+1
    int*   bsums = off + (N_NODES + 1);       // SCAN_NB (<=512)
    int*   nbr   = bsums + 512;               // NE

    size_t zero_elems = (size_t)2 * NF + (size_t)2 * NG * NF + NG + (size_t)2 * N_NODES;
    hipMemsetAsync(d_ws, 0, zero_elems * sizeof(float), stream);

    k_deg  <<<(NE + 255) / 256, 256, 0, stream>>>(edst, deg);
    k_stats<<<(N_NODES + SROWS - 1) / SROWS, 64, 0, stream>>>(x, gid, bsum, bsq, gsum, gsq, cnt);
    k_scan1<<<SCAN_NB, 256, 0, stream>>>(deg, bsums);
    k_scan2<<<1, 64, 0, stream>>>(bsums);
    k_scan3<<<SCAN_NB, 256, 0, stream>>>(deg, bsums, off);
    k_fill <<<(NE + 255) / 256, 256, 0, stream>>>(esrc, edst, off, cursor, nbr);
    k_final<<<N_NODES / 4, 256, 0, stream>>>(x, gamma, beta, lb, lg, la, ln, gid,
                                             bsum, bsq, gsum, gsq, cnt, off, nbr, out);
}

// Round 3
// 275.560 us; speedup vs baseline: 1.2950x; 1.2950x over previous
//
#include <hip/hip_runtime.h>

#define N_NODES 100000
#define NF      128
#define NE      600000
#define NG      1000
#define EPSF    1e-5f

#define SCHUNK  1024
#define SCAN_NB ((N_NODES + SCHUNK - 1) / SCHUNK)   // 98

// ---------------- degree count ----------------
__global__ void k_deg(const int* __restrict__ dst, int* __restrict__ deg) {
    int e = blockIdx.x * 256 + threadIdx.x;
    if (e < NE) atomicAdd(&deg[dst[e]], 1);
}

// ---------------- streaming stats: per-graph run-flush (batch derived later) ----------------
// 256 threads = 4 waves; each wave owns 8 contiguous rows. grid = 100000/32 = 3125.
__global__ __launch_bounds__(256) void k_stats(
    const float* __restrict__ x, const int* __restrict__ gid,
    float* __restrict__ gsum, float* __restrict__ gsq, int* __restrict__ cnt)
{
    const int wave = threadIdx.x >> 6;
    const int lane = threadIdx.x & 63;
    const int f = lane * 2;
    const int r0 = blockIdx.x * 32 + wave * 8;
    const int r1 = r0 + 8;

    float gsx = 0.f, gsy = 0.f, gqx = 0.f, gqy = 0.f;
    int cur = gid[r0];
    int runStart = r0;

    for (int r = r0; r < r1; ++r) {
        int g = gid[r];                  // wave-uniform
        if (g != cur) {
            atomicAdd(&gsum[cur * NF + f],     gsx);
            atomicAdd(&gsum[cur * NF + f + 1], gsy);
            atomicAdd(&gsq [cur * NF + f],     gqx);
            atomicAdd(&gsq [cur * NF + f + 1], gqy);
            if (lane == 0) atomicAdd(&cnt[cur], r - runStart);
            gsx = gsy = gqx = gqy = 0.f;
            cur = g; runStart = r;
        }
        const float2 v = *reinterpret_cast<const float2*>(x + (size_t)r * NF + f);
        gsx += v.x; gsy += v.y; gqx += v.x * v.x; gqy += v.y * v.y;
    }
    atomicAdd(&gsum[cur * NF + f],     gsx);
    atomicAdd(&gsum[cur * NF + f + 1], gsy);
    atomicAdd(&gsq [cur * NF + f],     gqx);
    atomicAdd(&gsq [cur * NF + f + 1], gqy);
    if (lane == 0) atomicAdd(&cnt[cur], r1 - runStart);
}

// ---------------- batch sums from graph tables: bsum[f] = sum_g gsum[g][f] ----------------
__global__ __launch_bounds__(256) void k_bred(
    const float* __restrict__ gsum, const float* __restrict__ gsq,
    float* __restrict__ bsum, float* __restrict__ bsq)
{
    int t = threadIdx.x, b = blockIdx.x;
    int f = t & 127, gl = t >> 7;        // 2 graph-lanes x 128 features
    float s = 0.f, q = 0.f;
#pragma unroll
    for (int k = 0; k < 8; ++k) {
        int g = b * 16 + gl * 8 + k;
        if (g < NG) { s += gsum[g * NF + f]; q += gsq[g * NF + f]; }
    }
    atomicAdd(&bsum[f], s);
    atomicAdd(&bsq[f], q);
}

// ---------------- 3-kernel exclusive scan of deg -> off ----------------
__global__ void k_scan1(const int* __restrict__ deg, int* __restrict__ bsums) {
    __shared__ int sdata[256];
    int b = blockIdx.x, t = threadIdx.x;
    int base = b * SCHUNK;
    int s = 0;
#pragma unroll
    for (int k = 0; k < 4; ++k) {
        int i = base + t * 4 + k;
        if (i < N_NODES) s += deg[i];
    }
    sdata[t] = s; __syncthreads();
    for (int st = 128; st > 0; st >>= 1) {
        if (t < st) sdata[t] += sdata[t + st];
        __syncthreads();
    }
    if (t == 0) bsums[b] = sdata[0];
}

__global__ void k_scan2(int* __restrict__ bsums) {
    if (threadIdx.x == 0 && blockIdx.x == 0) {
        int acc = 0;
        for (int i = 0; i < SCAN_NB; ++i) { int v = bsums[i]; bsums[i] = acc; acc += v; }
    }
}

__global__ void k_scan3(const int* __restrict__ deg, const int* __restrict__ bsums,
                        int* __restrict__ off) {
    __shared__ int sdata[256];
    int b = blockIdx.x, t = threadIdx.x;
    int base = b * SCHUNK;
    int loc[4]; int s = 0;
#pragma unroll
    for (int k = 0; k < 4; ++k) {
        int i = base + t * 4 + k;
        loc[k] = (i < N_NODES) ? deg[i] : 0;
        s += loc[k];
    }
    sdata[t] = s; __syncthreads();
    for (int st = 1; st < 256; st <<= 1) {
        int v = (t >= st) ? sdata[t - st] : 0;
        __syncthreads();
        sdata[t] += v;
        __syncthreads();
    }
    int run = bsums[b] + (sdata[t] - s);
#pragma unroll
    for (int k = 0; k < 4; ++k) {
        int i = base + t * 4 + k;
        if (i < N_NODES) { off[i] = run; run += loc[k]; }
    }
    if (b == 0 && t == 0) off[N_NODES] = NE;
}

// ---------------- CSR fill ----------------
__global__ void k_fill(const int* __restrict__ src, const int* __restrict__ dst,
                       const int* __restrict__ off, int* __restrict__ cursor,
                       int* __restrict__ nbr) {
    int e = blockIdx.x * 256 + threadIdx.x;
    if (e < NE) {
        int d = dst[e];
        int p = atomicAdd(&cursor[d], 1);
        nbr[off[d] + p] = src[e];
    }
}

// ---------------- prep: graph tables -> (mu, rstd) in place; fold feature constants ----------------
// fc[f*8] = { mb, rvb, w0*gamma/s, w1*gamma/s, w2*gamma/s, w3*gamma/s, beta, 0 }
__global__ __launch_bounds__(256) void k_prep(
    float* __restrict__ gsum, float* __restrict__ gsq, const int* __restrict__ cnt,
    const float* __restrict__ bsum, const float* __restrict__ bsq,
    const float* __restrict__ gamma, const float* __restrict__ beta,
    const float* __restrict__ lb, const float* __restrict__ lg,
    const float* __restrict__ la, const float* __restrict__ ln,
    float* __restrict__ fc)
{
    int b = blockIdx.x;
    if (b < (NG * NF) / 256) {           // 500 blocks: elementwise convert
        int idx = b * 256 + threadIdx.x;
        int g = idx >> 7;
        float c = (float)cnt[g]; if (c < 1.f) c = 1.f;
        float rc = 1.0f / c;
        float m = gsum[idx] * rc;
        float v = gsq[idx] * rc - m * m; if (v < 0.f) v = 0.f;
        gsum[idx] = m;
        gsq[idx]  = rsqrtf(v + EPSF);
    } else if (threadIdx.x < NF) {       // block 500: per-feature constants
        int f = threadIdx.x;
        float mb = bsum[f] * (1.0f / N_NODES);
        float vb = bsq[f] * (1.0f / N_NODES) - mb * mb;   // no clamp, matches reference
        float rvb = rsqrtf(vb + EPSF);
        float l0 = lb[f], l1 = lg[f], l2 = la[f], l3 = ln[f];
        float m = fmaxf(fmaxf(l0, l1), fmaxf(l2, l3));
        float w0 = __expf(l0 - m), w1 = __expf(l1 - m), w2 = __expf(l2 - m), w3 = __expf(l3 - m);
        float rs = gamma[f] / (w0 + w1 + w2 + w3);
        float* p = fc + f * 8;
        p[0] = mb; p[1] = rvb;
        p[2] = w0 * rs; p[3] = w1 * rs; p[4] = w2 * rs; p[5] = w3 * rs;
        p[6] = beta[f]; p[7] = 0.f;
    }
}

// ---------------- fused final ----------------
__global__ __launch_bounds__(256) void k_final(
    const float* __restrict__ x, const int* __restrict__ gid,
    const float* __restrict__ gmu, const float* __restrict__ grs,
    const float* __restrict__ fc,
    const int* __restrict__ off, const int* __restrict__ nbr,
    float* __restrict__ out)
{
    const int wave = threadIdx.x >> 6;
    const int lane = threadIdx.x & 63;
    const int i = blockIdx.x * 4 + wave;
    const int f = lane * 2;

    const float2 xi = *reinterpret_cast<const float2*>(x + (size_t)i * NF + f);

    // per-feature constants: {mb, rvb, w0, w1} {w2, w3, beta, pad}
    const float4 c0 = *reinterpret_cast<const float4*>(fc + f * 8);
    const float4 c1 = *reinterpret_cast<const float4*>(fc + f * 8 + 4);
    const float4 d0 = *reinterpret_cast<const float4*>(fc + (f + 1) * 8);
    const float4 d1 = *reinterpret_cast<const float4*>(fc + (f + 1) * 8 + 4);

    // ---- batch norm ----
    float xbx = (xi.x - c0.x) * c0.y;
    float xby = (xi.y - d0.x) * d0.y;

    // ---- graph norm ----
    const int g = gid[i];
    const float2 mg = *reinterpret_cast<const float2*>(gmu + (size_t)g * NF + f);
    const float2 rg = *reinterpret_cast<const float2*>(grs + (size_t)g * NF + f);
    float xgx = (xi.x - mg.x) * rg.x;
    float xgy = (xi.y - mg.y) * rg.y;

    // ---- node norm ----
    float s = xi.x + xi.y;
#pragma unroll
    for (int d = 1; d < 64; d <<= 1) s += __shfl_xor(s, d, 64);
    const float mn = s * (1.0f / NF);
    float dxx = xi.x - mn, dyy = xi.y - mn;
    float q = dxx * dxx + dyy * dyy;
#pragma unroll
    for (int d = 1; d < 64; d <<= 1) q += __shfl_xor(q, d, 64);
    const float rvn = rsqrtf(q * (1.0f / NF) + EPSF);
    float xnx = dxx * rvn, xny = dyy * rvn;

    // ---- adjacency norm: CSR gather, 4-wide unrolled for MLP ----
    const int e0 = off[i], e1 = off[i + 1];
    float asx = 0.f, asy = 0.f, aqx = 0.f, aqy = 0.f;
    int e = e0;
    for (; e + 4 <= e1; e += 4) {
        int j0 = nbr[e], j1 = nbr[e + 1], j2 = nbr[e + 2], j3 = nbr[e + 3];
        const float2 v0 = *reinterpret_cast<const float2*>(x + (size_t)j0 * NF + f);
        const float2 v1 = *reinterpret_cast<const float2*>(x + (size_t)j1 * NF + f);
        const float2 v2 = *reinterpret_cast<const float2*>(x + (size_t)j2 * NF + f);
        const float2 v3 = *reinterpret_cast<const float2*>(x + (size_t)j3 * NF + f);
        asx += v0.x; asy += v0.y; aqx += v0.x * v0.x; aqy += v0.y * v0.y;
        asx += v1.x; asy += v1.y; aqx += v1.x * v1.x; aqy += v1.y * v1.y;
        asx += v2.x; asy += v2.y; aqx += v2.x * v2.x; aqy += v2.y * v2.y;
        asx += v3.x; asy += v3.y; aqx += v3.x * v3.x; aqy += v3.y * v3.y;
    }
    for (; e < e1; ++e) {
        int j = nbr[e];
        const float2 v = *reinterpret_cast<const float2*>(x + (size_t)j * NF + f);
        asx += v.x; asy += v.y; aqx += v.x * v.x; aqy += v.y * v.y;
    }
    float dgc = (float)(e1 - e0); if (dgc < 1.f) dgc = 1.f;
    float rdg = 1.0f / dgc;
    float max_ = asx * rdg, may_ = asy * rdg;
    float vax = aqx * rdg - max_ * max_; if (vax < 0.f) vax = 0.f;
    float vay = aqy * rdg - may_ * may_; if (vay < 0.f) vay = 0.f;
    float xax = (xi.x - max_) * rsqrtf(vax + EPSF);
    float xay = (xi.y - may_) * rsqrtf(vay + EPSF);

    // ---- combine (weights pre-folded with gamma, softmax-normalized) ----
    float outx = c0.z * xbx + c0.w * xgx + c1.x * xax + c1.y * xnx + c1.z;
    float outy = d0.z * xby + d0.w * xgy + d1.x * xay + d1.y * xny + d1.z;
    *reinterpret_cast<float2*>(out + (size_t)i * NF + f) = make_float2(outx, outy);
}

extern "C" void kernel_launch(void* const* d_in, const int* in_sizes, int n_in,
                              void* d_out, int out_size, void* d_ws, size_t ws_size,
                              hipStream_t stream) {
    const float* x     = (const float*)d_in[0];
    const float* gamma = (const float*)d_in[1];
    const float* beta  = (const float*)d_in[2];
    const float* lb    = (const float*)d_in[3];
    const float* lg    = (const float*)d_in[4];
    const float* la    = (const float*)d_in[5];
    const float* ln    = (const float*)d_in[6];
    const int*   gid   = (const int*)d_in[7];
    const int*   esrc  = (const int*)d_in[8];
    const int*   edst  = (const int*)d_in[9];
    float*       out   = (float*)d_out;

    // ---- workspace layout (4B units); zeroed region first ----
    float* ws    = (float*)d_ws;
    float* bsum  = ws;                              // NF
    float* bsq   = bsum + NF;                       // NF
    float* gsum  = bsq + NF;                        // NG*NF  (becomes gmu)
    float* gsq   = gsum + (size_t)NG * NF;          // NG*NF  (becomes grs)
    int*   cnt   = (int*)(gsq + (size_t)NG * NF);   // NG
    int*   deg   = cnt + NG;                        // N
    int*   cursor= deg + N_NODES;                   // N
    // zeroed region ends here
    int*   off   = cursor + N_NODES;                // N+1
    int*   bsums = off + (N_NODES + 1);             // <=512
    int*   nbr   = bsums + 512;                     // NE
    float* fc    = (float*)(nbr + NE);              // NF*8

    size_t zero_elems = (size_t)2 * NF + (size_t)2 * NG * NF + NG + (size_t)2 * N_NODES;
    hipMemsetAsync(d_ws, 0, zero_elems * sizeof(float), stream);

    k_deg  <<<(NE + 255) / 256, 256, 0, stream>>>(edst, deg);
    k_stats<<<N_NODES / 32, 256, 0, stream>>>(x, gid, gsum, gsq, cnt);
    k_bred <<<64, 256, 0, stream>>>(gsum, gsq, bsum, bsq);
    k_scan1<<<SCAN_NB, 256, 0, stream>>>(deg, bsums);
    k_scan2<<<1, 64, 0, stream>>>(bsums);
    k_scan3<<<SCAN_NB, 256, 0, stream>>>(deg, bsums, off);
    k_fill <<<(NE + 255) / 256, 256, 0, stream>>>(esrc, edst, off, cursor, nbr);
    k_prep <<<(NG * NF) / 256 + 1, 256, 0, stream>>>(gsum, gsq, cnt, bsum, bsq,
                                                     gamma, beta, lb, lg, la, ln, fc);
    k_final<<<N_NODES / 4, 256, 0, stream>>>(x, gid, gsum, gsq, fc, off, nbr, out);
}